// Round 2
// baseline (245.254 us; speedup 1.0000x reference)
//
#include <hip/hip_runtime.h>
#include <hip/hip_bf16.h>

#define N_NODES 50000
#define N_EDGES 800000
#define ETOT    (N_EDGES + N_NODES)   // 850000 with self-loops
#define STRIDE  64                    // fixed CSR slots per node (u16 entries)
#define IN_CH   16
#define HID     32
#define HEADS   4
#define C1      (HEADS * HID)         // 128
#define NEG     0.2f
#define NCOPY   8                     // pseudo-XCD histogram copies

#define DEG_BLOCKS ((ETOT / 4 + 255) / 256)   // 831 (4 edges/thread)
#define NGROUPS    (N_NODES / 4)              // 12500 node-groups (4 nodes each)
#define H1_BLOCKS  2048                       // grid-stride over node-groups

typedef unsigned short u16;
typedef unsigned int   u32;

__device__ __forceinline__ float bf2f(u16 b) {
    return __uint_as_float(((u32)b) << 16);
}

__device__ __forceinline__ u16 f2bf(float f) {
    __hip_bfloat16 hb = __float2bfloat16(f);
    return *(u16*)&hb;
}

__device__ __forceinline__ int clampn(int v) {
    return v < 0 ? 0 : (v >= N_NODES ? N_NODES - 1 : v);
}

// edge endpoint read, int32 vs int64 layout. which: 0=src, 1=dst. e < N_EDGES.
__device__ __forceinline__ int eidx(const int* ei, int e, int i64, int which) {
    int v = i64 ? ei[2 * (which * N_EDGES + e)] : ei[which * N_EDGES + e];
    return clampn(v);
}

__device__ __forceinline__ float cvt(const void* src, int i, int bf) {
    return bf ? bf2f(((const u16*)src)[i]) : ((const float*)src)[i];
}

// ---- per-wave dtype probes (all 64 lanes active; L2-hot 512B reads) ----
__device__ __forceinline__ int probe_bf_wave(const u16* xb) {
    int l = threadIdx.x & 63;
    int my = 0;
#pragma unroll
    for (int k = 0; k < 4; k++) {
        float f = bf2f(xb[l * 4 + k]);
        float a = fabsf(f);
        if (f == 0.0f || (a > 9.5e-7f && a < 1.05e6f)) my++;
    }
#pragma unroll
    for (int m = 32; m; m >>= 1) my += __shfl_xor(my, m);
    return my >= 224;   // true bf16 -> ~256 sane; fp32 misread -> ~148
}

__device__ __forceinline__ int probe_i64_wave(const int* ei32) {
    int l = threadIdx.x & 63;
    int nz = (l < 32 && ei32[2 * l + 1] != 0) ? 1 : 0;
#pragma unroll
    for (int m = 32; m; m >>= 1) nz += __shfl_xor(nz, m);
    return nz == 0;     // int64: high words of src[0..31] all zero
}

// ---- pass A: per-copy degree histogram. Copy = blockIdx&7 so each copy's
// cache lines live on ONE XCD's L2 (round-robin dispatch) -> no cross-XCD
// line migration on the atomics. dst-only reads.
__launch_bounds__(256)
__global__ void k_count(const int* __restrict__ ei, u32* __restrict__ degs8) {
    int i64 = probe_i64_wave(ei);
    int blk = blockIdx.x;
    int e0 = (blk * 256 + (int)threadIdx.x) * 4;
    if (e0 >= ETOT) return;           // ETOT % 4 == 0: quads never straddle
    u32* cnt = degs8 + (size_t)(blk & (NCOPY - 1)) * N_NODES;
#pragma unroll
    for (int j = 0; j < 4; j++) {
        int e = e0 + j;
        int d = (e < N_EDGES) ? eidx(ei, e, i64, 1) : (e - N_EDGES);
        atomicAdd(&cnt[d], 1u);
    }
}

// ---- prefix: per node, exclusive scan over the 8 copies -> absolute slot
// bases off8[c][n] = n*STRIDE + sum_{c'<c} cnt[c'][n]; degs[n] = total.
__launch_bounds__(256)
__global__ void k_prefix(const u32* __restrict__ degs8, u32* __restrict__ off8,
                         int* __restrict__ degs) {
    int n = blockIdx.x * 256 + (int)threadIdx.x;
    if (n >= N_NODES) return;
    u32 tot = 0;
#pragma unroll
    for (int c = 0; c < NCOPY; c++) {
        u32 cn = degs8[(size_t)c * N_NODES + n];
        off8[(size_t)c * N_NODES + n] = (u32)n * STRIDE + tot;
        tot += cn;
    }
    degs[n] = (int)tot;               // total incl. self-loop
}

// ---- pass B: fill. Same edge->copy assignment as k_count (blk&7), so each
// copy's running-offset atomics are again XCD-local. Slot known at return ->
// scatter csr directly.
__device__ __forceinline__ void dev_fill(const int* __restrict__ ei,
                                         u32* __restrict__ off8,
                                         u16* __restrict__ csr, int blk) {
    int i64 = probe_i64_wave(ei);
    int e0 = (blk * 256 + (int)threadIdx.x) * 4;
    if (e0 >= ETOT) return;
    u32* off = off8 + (size_t)(blk & (NCOPY - 1)) * N_NODES;
#pragma unroll
    for (int j = 0; j < 4; j++) {
        int e = e0 + j;
        int s, d;
        if (e < N_EDGES) { s = eidx(ei, e, i64, 0); d = eidx(ei, e, i64, 1); }
        else             { s = d = e - N_EDGES; }
        u32 slot = atomicAdd(&off[d], 1u);
        if (slot < (u32)d * STRIDE + STRIDE) csr[slot] = (u16)s;
    }
}

// ---- h1: register-resident weights, zero LDS, zero bpermute in inner loop.
// One wave per node (4 waves/block); lane l owns channels 2l,2l+1.
__device__ __forceinline__ void dev_h1(const void* __restrict__ x,
                                       const void* __restrict__ W1,
                                       const void* __restrict__ a_s,
                                       const void* __restrict__ a_d,
                                       u32* __restrict__ h1u,
                                       float* __restrict__ as1,
                                       float* __restrict__ ad1, int blk) {
    int bf = probe_bf_wave((const u16*)x);
    if (blk == 0 && threadIdx.x < 4) as1[N_NODES * 4 + threadIdx.x] = -1e30f;
    if (blk == 0 && threadIdx.x >= 64 && threadIdx.x < 128)
        h1u[N_NODES * 64 + (threadIdx.x - 64)] = 0;   // sentinel row: exact 0

    int w = threadIdx.x >> 6, l = threadIdx.x & 63;

    float wa[IN_CH], wb[IN_CH];            // W1[:, 2l] and W1[:, 2l+1]
    if (bf) {
        const u32* w32 = (const u32*)W1;   // u32 = channels (2l, 2l+1) of row k
#pragma unroll
        for (int k = 0; k < IN_CH; k++) {
            u32 v = w32[k * 64 + l];
            wa[k] = bf2f((u16)(v & 0xFFFF));
            wb[k] = bf2f((u16)(v >> 16));
        }
    } else {
        const float2* w64 = (const float2*)W1;
#pragma unroll
        for (int k = 0; k < IN_CH; k++) {
            float2 v = w64[k * 64 + l];
            wa[k] = v.x; wb[k] = v.y;
        }
    }
    float asa, asb, ada, adb;              // a_src/a_dst coeffs for c0,c1
    if (bf) {
        u32 vs = ((const u32*)a_s)[l], vd = ((const u32*)a_d)[l];
        asa = bf2f((u16)(vs & 0xFFFF)); asb = bf2f((u16)(vs >> 16));
        ada = bf2f((u16)(vd & 0xFFFF)); adb = bf2f((u16)(vd >> 16));
    } else {
        float2 vs = ((const float2*)a_s)[l], vd = ((const float2*)a_d)[l];
        asa = vs.x; asb = vs.y; ada = vd.x; adb = vd.y;
    }

    for (int g = blk; g < NGROUPS; g += H1_BLOCKS) {
        int n = g * 4 + w;
        float xr[IN_CH];
        if (bf) {
            const uint4* xp = (const uint4*)((const u16*)x + (size_t)n * IN_CH);
            uint4 q0 = xp[0], q1 = xp[1];
            u32 qq[8] = {q0.x, q0.y, q0.z, q0.w, q1.x, q1.y, q1.z, q1.w};
#pragma unroll
            for (int k = 0; k < 8; k++) {
                xr[2 * k]     = bf2f((u16)(qq[k] & 0xFFFF));
                xr[2 * k + 1] = bf2f((u16)(qq[k] >> 16));
            }
        } else {
            const float4* xp = (const float4*)((const float*)x + (size_t)n * IN_CH);
#pragma unroll
            for (int k = 0; k < 4; k++) {
                float4 q = xp[k];
                xr[4 * k] = q.x; xr[4 * k + 1] = q.y;
                xr[4 * k + 2] = q.z; xr[4 * k + 3] = q.w;
            }
        }
        float acc0 = 0.f, acc1 = 0.f;
#pragma unroll
        for (int k = 0; k < IN_CH; k++) {
            acc0 += xr[k] * wa[k];
            acc1 += xr[k] * wb[k];
        }
        h1u[n * 64 + l] = (u32)f2bf(acc0) | ((u32)f2bf(acc1) << 16);

        float ps = acc0 * asa + acc1 * asb;
        float pd = acc0 * ada + acc1 * adb;
#pragma unroll
        for (int m = 8; m; m >>= 1) { ps += __shfl_xor(ps, m); pd += __shfl_xor(pd, m); }
        if ((l & 15) == 0) {
            int hd = l >> 4;
            as1[n * 4 + hd] = ps;
            ad1[n * 4 + hd] = pd;
        }
    }
}

// ---- dispatch wrapper: fill and h1 co-dispatched (independent); h1 hides
// under the fill's scatter tail.
__launch_bounds__(256)
__global__ void k_fill_h1(const void* __restrict__ x, const int* __restrict__ ei,
                          const void* __restrict__ W1, const void* __restrict__ a_s,
                          const void* __restrict__ a_d,
                          u32* __restrict__ off8, u16* __restrict__ csr,
                          u32* __restrict__ h1u, float* __restrict__ as1,
                          float* __restrict__ ad1) {
    if (blockIdx.x < DEG_BLOCKS) { dev_fill(ei, off8, csr, blockIdx.x); return; }
    dev_h1(x, W1, a_s, a_d, h1u, as1, ad1, blockIdx.x - DEG_BLOCKS);
}

// ---- layer-1 gather: r13 loop + batch-ahead csr prefetch + sw dedup.
// One wave per dst node; lane l owns channels 2l,2l+1; own head hd = l>>4.
// Weight duty: edge je=l&7 with head jh=(l>>3)&3 (lanes 32-63 duplicate).
__launch_bounds__(256)
__global__ void k_gather1(const void* __restrict__ x,
                          const int* __restrict__ degs, const u16* __restrict__ csr,
                          const u32* __restrict__ h1u,
                          const float* __restrict__ as1, const float* __restrict__ ad1,
                          const void* __restrict__ b1, const void* __restrict__ W2,
                          const void* __restrict__ a2s, const void* __restrict__ a2d,
                          float* __restrict__ h2, float* __restrict__ as2,
                          float* __restrict__ ad2) {
    int bf = probe_bf_wave((const u16*)x);
    int n = blockIdx.x * 4 + (threadIdx.x >> 6);
    int l = threadIdx.x & 63;
    int hd = l >> 4;                 // own head (channel ownership)
    int je = l & 7;                  // weight duty: edge slot
    int jh = (l >> 3) & 3;           // weight duty: head
    float advb = ad1[n * 4 + jh];
    int deg = degs[n];               // total count incl. self-loop; >=1
    deg = deg > STRIDE ? STRIDE : deg;
    int nb = (deg + 7) >> 3;         // 8-padded batches
    const u16* row = csr + (size_t)n * STRIDE;
    float acc0 = 0.f, acc1 = 0.f, swd = 0.f;

    int se = (int)row[je];
    if (se >= N_NODES) se = N_NODES;
    for (int b = 0; b < nb; b++) {
        int se_next = 0xFFFF;                        // prefetch next batch's csr
        if (b + 1 < nb) se_next = (int)row[(b + 1) * 8 + je];
        float t = as1[se * 4 + jh] + advb;           // sentinel: -1e30
        t = t > 0.f ? t : NEG * t;
        float wm = __expf(t);                        // sentinel: 0
        swd += wm;
#pragma unroll
        for (int j = 0; j < 8; j++) {
            int   sj = __shfl(se, j);                // edge j's src (const idx)
            float wj = __shfl(wm, hd * 8 + j);       // edge j's weight, my head
            u32 p = h1u[sj * 64 + l];                // row N: zeroed, w = 0
            acc0 += wj * bf2f((u16)(p & 0xFFFF));
            acc1 += wj * bf2f((u16)(p >> 16));
        }
        se = se_next >= N_NODES ? N_NODES : se_next;
    }

    // sw[jh] = sum of swd over the 8 duty lanes of that head
    swd += __shfl_xor(swd, 1);
    swd += __shfl_xor(swd, 2);
    swd += __shfl_xor(swd, 4);
    float sw = __shfl(swd, hd * 8);        // my head's weight sum

    float inv = 1.0f / sw;                 // sw > 0 guaranteed by self-loop
    float v0 = acc0 * inv + cvt(b1, 2 * l, bf);
    float v1 = acc1 * inv + cvt(b1, 2 * l + 1, bf);
    v0 = v0 > 0.f ? v0 : 0.f;
    v1 = v1 > 0.f ? v1 : 0.f;
    float p0 = v0 * cvt(W2, 4 * l,     bf) + v1 * cvt(W2, 4 * l + 2, bf);
    float p1 = v0 * cvt(W2, 4 * l + 1, bf) + v1 * cvt(W2, 4 * l + 3, bf);
#pragma unroll
    for (int d = 32; d; d >>= 1) { p0 += __shfl_down(p0, d); p1 += __shfl_down(p1, d); }
    if (l == 0) {
        h2[n * 2] = p0; h2[n * 2 + 1] = p1;
        as2[n] = p0 * cvt(a2s, 0, bf) + p1 * cvt(a2s, 1, bf);
        ad2[n] = p0 * cvt(a2d, 0, bf) + p1 * cvt(a2d, 1, bf);
    }
}

// ---- layer-2 gather: 16 lanes per dst node, exact trips, shuffle reduce ----
__launch_bounds__(256)
__global__ void k_gather2(const void* __restrict__ x,
                          const int* __restrict__ degs, const u16* __restrict__ csr,
                          const float* __restrict__ h2, const float* __restrict__ as2,
                          const float* __restrict__ ad2, const void* __restrict__ b2,
                          void* __restrict__ out) {
    int bf = probe_bf_wave((const u16*)x);
    int n = blockIdx.x * 16 + (threadIdx.x >> 4);
    int g = threadIdx.x & 15;
    float adv = ad2[n], a0 = 0.f, a1 = 0.f, sw = 0.f;
    int deg = degs[n];                       // total count incl. self-loop
    deg = deg > STRIDE ? STRIDE : deg;
    const u16* row = csr + (size_t)n * STRIDE;
    for (int k = g; k < deg; k += 16) {      // never reads pad slots
        int s = (int)row[k];
        float lg = as2[s] + adv;
        lg = lg > 0.f ? lg : NEG * lg;
        float w = __expf(lg);
        float2 hv = ((const float2*)h2)[s];
        a0 += w * hv.x;
        a1 += w * hv.y;
        sw += w;
    }
#pragma unroll
    for (int m = 8; m; m >>= 1) {
        a0 += __shfl_xor(a0, m); a1 += __shfl_xor(a1, m); sw += __shfl_xor(sw, m);
    }
    if (g == 0) {
        float inv = 1.0f / sw;
        float o0 = a0 * inv + cvt(b2, 0, bf);
        float o1 = a1 * inv + cvt(b2, 1, bf);
        if (bf) {
            ((u32*)out)[n] = (u32)f2bf(o0) | ((u32)f2bf(o1) << 16);
        } else {
            ((float2*)out)[n] = make_float2(o0, o1);
        }
    }
}

extern "C" void kernel_launch(void* const* d_in, const int* in_sizes, int n_in,
                              void* d_out, int out_size, void* d_ws, size_t ws_size,
                              hipStream_t stream) {
    const void* x    = d_in[0];
    const int*  ei   = (const int*)d_in[1];
    const void* W1   = d_in[2];
    const void* a_s1 = d_in[3];
    const void* a_d1 = d_in[4];
    const void* b1   = d_in[5];
    const void* W2   = d_in[6];
    const void* a_s2 = d_in[7];
    const void* a_d2 = d_in[8];
    const void* b2   = d_in[9];

    // ---- ws carve: ~25.0 MB ----
    char* p = (char*)d_ws;
    int*   degs  = (int*)p;   p += ((size_t)N_NODES * 4 + 255) & ~255;            // 200 KB
    u32*   degs8 = (u32*)p;   p += (size_t)NCOPY * N_NODES * 4;                   // 1.6 MB (zero init)
    u32*   off8  = (u32*)p;   p += (size_t)NCOPY * N_NODES * 4;                   // 1.6 MB (prefix-written)
    u16*   csr   = (u16*)p;   p += (size_t)N_NODES * STRIDE * 2;                  // 6.4 MB (0xFF init)
    u32*   h1u   = (u32*)p;   p += (size_t)(N_NODES + 1) * 64 * 4;                // 12.8 MB (+ row N)
    float* as1   = (float*)p; p += (size_t)(N_NODES + 1) * HEADS * 4;             // + sentinel
    float* ad1   = (float*)p; p += (size_t)N_NODES * HEADS * 4;
    float* h2    = (float*)p; p += (size_t)N_NODES * 2 * 4;
    float* as2   = (float*)p; p += (size_t)N_NODES * 4;
    float* ad2   = (float*)p; p += (size_t)N_NODES * 4;

    hipMemsetAsync(degs8, 0x00, (size_t)NCOPY * N_NODES * 4, stream);   // counts = 0
    hipMemsetAsync(csr,   0xFF, (size_t)N_NODES * STRIDE * 2, stream);  // pad sentinels

    k_count<<<DEG_BLOCKS, 256, 0, stream>>>(ei, degs8);
    k_prefix<<<(N_NODES + 255) / 256, 256, 0, stream>>>(degs8, off8, degs);
    k_fill_h1<<<DEG_BLOCKS + H1_BLOCKS, 256, 0, stream>>>(
        x, ei, W1, a_s1, a_d1, off8, csr, h1u, as1, ad1);
    k_gather1<<<N_NODES / 4, 256, 0, stream>>>(
        x, degs, csr, h1u, as1, ad1, b1, W2, a_s2, a_d2, h2, as2, ad2);
    k_gather2<<<N_NODES / 16, 256, 0, stream>>>(
        x, degs, csr, h2, as2, ad2, b2, d_out);
}

// Round 3
// 198.984 us; speedup vs baseline: 1.2325x; 1.2325x over previous
//
#include <hip/hip_runtime.h>
#include <hip/hip_bf16.h>

#define N_NODES 50000
#define N_EDGES 800000
#define ETOT    (N_EDGES + N_NODES)   // 850000 with self-loops
#define STRIDE  64                    // fixed CSR slots per node (u16 entries)
#define IN_CH   16
#define HID     32
#define HEADS   4
#define C1      (HEADS * HID)         // 128
#define NEG     0.2f
#define NSLICE  8                     // dst-range slices (one per XCD)
#define SLICE_N (N_NODES / NSLICE)    // 6250 nodes per slice

#define DEG_BLOCKS  ((ETOT / 4 + 255) / 256)   // 831 edge-chunks (4 edges/thread)
#define FILL_BLOCKS (NSLICE * DEG_BLOCKS)      // 6648: slice = blk&7, chunk = blk>>3
#define NGROUPS     (N_NODES / 4)              // 12500 node-groups (4 nodes each)
#define H1_BLOCKS   2048                       // grid-stride over node-groups

typedef unsigned short u16;
typedef unsigned int   u32;

__device__ __forceinline__ float bf2f(u16 b) {
    return __uint_as_float(((u32)b) << 16);
}

__device__ __forceinline__ u16 f2bf(float f) {
    __hip_bfloat16 hb = __float2bfloat16(f);
    return *(u16*)&hb;
}

__device__ __forceinline__ int clampn(int v) {
    return v < 0 ? 0 : (v >= N_NODES ? N_NODES - 1 : v);
}

// edge endpoint read, int32 vs int64 layout. which: 0=src, 1=dst. e < N_EDGES.
__device__ __forceinline__ int eidx(const int* ei, int e, int i64, int which) {
    int v = i64 ? ei[2 * (which * N_EDGES + e)] : ei[which * N_EDGES + e];
    return clampn(v);
}

__device__ __forceinline__ float cvt(const void* src, int i, int bf) {
    return bf ? bf2f(((const u16*)src)[i]) : ((const float*)src)[i];
}

// ---- per-wave dtype probes (all 64 lanes active; L2-hot 512B reads) ----
__device__ __forceinline__ int probe_bf_wave(const u16* xb) {
    int l = threadIdx.x & 63;
    int my = 0;
#pragma unroll
    for (int k = 0; k < 4; k++) {
        float f = bf2f(xb[l * 4 + k]);
        float a = fabsf(f);
        if (f == 0.0f || (a > 9.5e-7f && a < 1.05e6f)) my++;
    }
#pragma unroll
    for (int m = 32; m; m >>= 1) my += __shfl_xor(my, m);
    return my >= 224;   // true bf16 -> ~256 sane; fp32 misread -> ~148
}

__device__ __forceinline__ int probe_i64_wave(const int* ei32) {
    int l = threadIdx.x & 63;
    int nz = (l < 32 && ei32[2 * l + 1] != 0) ? 1 : 0;
#pragma unroll
    for (int m = 32; m; m >>= 1) nz += __shfl_xor(nz, m);
    return nz == 0;     // int64: high words of src[0..31] all zero
}

// ---- deg+fill, dst-range sliced: block handles edge chunk (blk>>3) but
// commits ONLY edges with dst in slice (blk&7)'s node range. With round-robin
// block->XCD dispatch, slice s runs on XCD s: each degs counter and each csr
// line is touched by exactly ONE XCD's L2 -> no cross-XCD dirty-line
// amplification (round-2 counters showed csr scatter dirty in 8 L2s = ~51 MB
// writeback). Edge list is scanned 8x (L3-absorbed). Edge order within a csr
// row is irrelevant: segment softmax sums are order-independent.
__device__ __forceinline__ void dev_degfill(const int* __restrict__ ei,
                                            int* __restrict__ degs,
                                            u16* __restrict__ csr, int blk) {
    int slice = blk & (NSLICE - 1);
    int chunk = blk >> 3;
    int i64 = probe_i64_wave(ei);
    int e0 = (chunk * 256 + (int)threadIdx.x) * 4;
    if (e0 >= ETOT) return;           // ETOT % 4 == 0: quads never straddle
    int lo = slice * SLICE_N, hi = lo + SLICE_N;
    int s[4], d[4];
#pragma unroll
    for (int j = 0; j < 4; j++) {     // load src+dst unconditionally: coalesced
        int e = e0 + j;
        if (e < N_EDGES) { s[j] = eidx(ei, e, i64, 0); d[j] = eidx(ei, e, i64, 1); }
        else             { s[j] = d[j] = e - N_EDGES; }
    }
#pragma unroll
    for (int j = 0; j < 4; j++) {
        if (d[j] >= lo && d[j] < hi) {
            u32 r = (u32)atomicAdd(&degs[d[j]], 1) + 1u;   // -1 init -> 0-based
            if (r < STRIDE) csr[(size_t)d[j] * STRIDE + r] = (u16)s[j];
        }
    }
}

// ---- h1: register-resident weights, zero LDS, zero bpermute in inner loop.
// One wave per node (4 waves/block); lane l owns channels 2l,2l+1.
__device__ __forceinline__ void dev_h1(const void* __restrict__ x,
                                       const void* __restrict__ W1,
                                       const void* __restrict__ a_s,
                                       const void* __restrict__ a_d,
                                       u32* __restrict__ h1u,
                                       float* __restrict__ as1,
                                       float* __restrict__ ad1, int blk) {
    int bf = probe_bf_wave((const u16*)x);
    if (blk == 0 && threadIdx.x < 4) as1[N_NODES * 4 + threadIdx.x] = -1e30f;
    if (blk == 0 && threadIdx.x >= 64 && threadIdx.x < 128)
        h1u[N_NODES * 64 + (threadIdx.x - 64)] = 0;   // sentinel row: exact 0

    int w = threadIdx.x >> 6, l = threadIdx.x & 63;

    float wa[IN_CH], wb[IN_CH];            // W1[:, 2l] and W1[:, 2l+1]
    if (bf) {
        const u32* w32 = (const u32*)W1;   // u32 = channels (2l, 2l+1) of row k
#pragma unroll
        for (int k = 0; k < IN_CH; k++) {
            u32 v = w32[k * 64 + l];
            wa[k] = bf2f((u16)(v & 0xFFFF));
            wb[k] = bf2f((u16)(v >> 16));
        }
    } else {
        const float2* w64 = (const float2*)W1;
#pragma unroll
        for (int k = 0; k < IN_CH; k++) {
            float2 v = w64[k * 64 + l];
            wa[k] = v.x; wb[k] = v.y;
        }
    }
    float asa, asb, ada, adb;              // a_src/a_dst coeffs for c0,c1
    if (bf) {
        u32 vs = ((const u32*)a_s)[l], vd = ((const u32*)a_d)[l];
        asa = bf2f((u16)(vs & 0xFFFF)); asb = bf2f((u16)(vs >> 16));
        ada = bf2f((u16)(vd & 0xFFFF)); adb = bf2f((u16)(vd >> 16));
    } else {
        float2 vs = ((const float2*)a_s)[l], vd = ((const float2*)a_d)[l];
        asa = vs.x; asb = vs.y; ada = vd.x; adb = vd.y;
    }

    for (int g = blk; g < NGROUPS; g += H1_BLOCKS) {
        int n = g * 4 + w;
        float xr[IN_CH];
        if (bf) {
            const uint4* xp = (const uint4*)((const u16*)x + (size_t)n * IN_CH);
            uint4 q0 = xp[0], q1 = xp[1];
            u32 qq[8] = {q0.x, q0.y, q0.z, q0.w, q1.x, q1.y, q1.z, q1.w};
#pragma unroll
            for (int k = 0; k < 8; k++) {
                xr[2 * k]     = bf2f((u16)(qq[k] & 0xFFFF));
                xr[2 * k + 1] = bf2f((u16)(qq[k] >> 16));
            }
        } else {
            const float4* xp = (const float4*)((const float*)x + (size_t)n * IN_CH);
#pragma unroll
            for (int k = 0; k < 4; k++) {
                float4 q = xp[k];
                xr[4 * k] = q.x; xr[4 * k + 1] = q.y;
                xr[4 * k + 2] = q.z; xr[4 * k + 3] = q.w;
            }
        }
        float acc0 = 0.f, acc1 = 0.f;
#pragma unroll
        for (int k = 0; k < IN_CH; k++) {
            acc0 += xr[k] * wa[k];
            acc1 += xr[k] * wb[k];
        }
        h1u[n * 64 + l] = (u32)f2bf(acc0) | ((u32)f2bf(acc1) << 16);

        float ps = acc0 * asa + acc1 * asb;
        float pd = acc0 * ada + acc1 * adb;
#pragma unroll
        for (int m = 8; m; m >>= 1) { ps += __shfl_xor(ps, m); pd += __shfl_xor(pd, m); }
        if ((l & 15) == 0) {
            int hd = l >> 4;
            as1[n * 4 + hd] = ps;
            ad1[n * 4 + hd] = pd;
        }
    }
}

// ---- dispatch wrapper: sliced deg+fill and h1 co-dispatched (independent) ----
__launch_bounds__(256)
__global__ void k_fill_h1(const void* __restrict__ x, const int* __restrict__ ei,
                          const void* __restrict__ W1, const void* __restrict__ a_s,
                          const void* __restrict__ a_d,
                          int* __restrict__ degs, u16* __restrict__ csr,
                          u32* __restrict__ h1u, float* __restrict__ as1,
                          float* __restrict__ ad1) {
    if (blockIdx.x < FILL_BLOCKS) { dev_degfill(ei, degs, csr, blockIdx.x); return; }
    dev_h1(x, W1, a_s, a_d, h1u, as1, ad1, blockIdx.x - FILL_BLOCKS);
}

// ---- layer-1 gather: r13 loop + batch-ahead csr prefetch + sw dedup.
// One wave per dst node; lane l owns channels 2l,2l+1; own head hd = l>>4.
// Weight duty: edge je=l&7 with head jh=(l>>3)&3 (lanes 32-63 duplicate).
__launch_bounds__(256)
__global__ void k_gather1(const void* __restrict__ x,
                          const int* __restrict__ degs, const u16* __restrict__ csr,
                          const u32* __restrict__ h1u,
                          const float* __restrict__ as1, const float* __restrict__ ad1,
                          const void* __restrict__ b1, const void* __restrict__ W2,
                          const void* __restrict__ a2s, const void* __restrict__ a2d,
                          float* __restrict__ h2, float* __restrict__ as2,
                          float* __restrict__ ad2) {
    int bf = probe_bf_wave((const u16*)x);
    int n = blockIdx.x * 4 + (threadIdx.x >> 6);
    int l = threadIdx.x & 63;
    int hd = l >> 4;                 // own head (channel ownership)
    int je = l & 7;                  // weight duty: edge slot
    int jh = (l >> 3) & 3;           // weight duty: head
    float advb = ad1[n * 4 + jh];
    int deg = degs[n] + 1;           // -1-init histogram; >=1 (self-loop)
    deg = deg > STRIDE ? STRIDE : deg;
    int nb = (deg + 7) >> 3;         // 8-padded batches
    const u16* row = csr + (size_t)n * STRIDE;
    float acc0 = 0.f, acc1 = 0.f, swd = 0.f;

    int se = (int)row[je];
    if (se >= N_NODES) se = N_NODES;
    for (int b = 0; b < nb; b++) {
        int se_next = 0xFFFF;                        // prefetch next batch's csr
        if (b + 1 < nb) se_next = (int)row[(b + 1) * 8 + je];
        float t = as1[se * 4 + jh] + advb;           // sentinel: -1e30
        t = t > 0.f ? t : NEG * t;
        float wm = __expf(t);                        // sentinel: 0
        swd += wm;
#pragma unroll
        for (int j = 0; j < 8; j++) {
            int   sj = __shfl(se, j);                // edge j's src (const idx)
            float wj = __shfl(wm, hd * 8 + j);       // edge j's weight, my head
            u32 p = h1u[sj * 64 + l];                // row N: zeroed, w = 0
            acc0 += wj * bf2f((u16)(p & 0xFFFF));
            acc1 += wj * bf2f((u16)(p >> 16));
        }
        se = se_next >= N_NODES ? N_NODES : se_next;
    }

    // sw[jh] = sum of swd over the 8 duty lanes of that head
    swd += __shfl_xor(swd, 1);
    swd += __shfl_xor(swd, 2);
    swd += __shfl_xor(swd, 4);
    float sw = __shfl(swd, hd * 8);        // my head's weight sum

    float inv = 1.0f / sw;                 // sw > 0 guaranteed by self-loop
    float v0 = acc0 * inv + cvt(b1, 2 * l, bf);
    float v1 = acc1 * inv + cvt(b1, 2 * l + 1, bf);
    v0 = v0 > 0.f ? v0 : 0.f;
    v1 = v1 > 0.f ? v1 : 0.f;
    float p0 = v0 * cvt(W2, 4 * l,     bf) + v1 * cvt(W2, 4 * l + 2, bf);
    float p1 = v0 * cvt(W2, 4 * l + 1, bf) + v1 * cvt(W2, 4 * l + 3, bf);
#pragma unroll
    for (int d = 32; d; d >>= 1) { p0 += __shfl_down(p0, d); p1 += __shfl_down(p1, d); }
    if (l == 0) {
        h2[n * 2] = p0; h2[n * 2 + 1] = p1;
        as2[n] = p0 * cvt(a2s, 0, bf) + p1 * cvt(a2s, 1, bf);
        ad2[n] = p0 * cvt(a2d, 0, bf) + p1 * cvt(a2d, 1, bf);
    }
}

// ---- layer-2 gather: 16 lanes per dst node, exact trips, shuffle reduce ----
__launch_bounds__(256)
__global__ void k_gather2(const void* __restrict__ x,
                          const int* __restrict__ degs, const u16* __restrict__ csr,
                          const float* __restrict__ h2, const float* __restrict__ as2,
                          const float* __restrict__ ad2, const void* __restrict__ b2,
                          void* __restrict__ out) {
    int bf = probe_bf_wave((const u16*)x);
    int n = blockIdx.x * 16 + (threadIdx.x >> 4);
    int g = threadIdx.x & 15;
    float adv = ad2[n], a0 = 0.f, a1 = 0.f, sw = 0.f;
    int deg = degs[n] + 1;                   // -1-init histogram
    deg = deg > STRIDE ? STRIDE : deg;
    const u16* row = csr + (size_t)n * STRIDE;
    for (int k = g; k < deg; k += 16) {      // never reads pad slots
        int s = (int)row[k];
        float lg = as2[s] + adv;
        lg = lg > 0.f ? lg : NEG * lg;
        float w = __expf(lg);
        float2 hv = ((const float2*)h2)[s];
        a0 += w * hv.x;
        a1 += w * hv.y;
        sw += w;
    }
#pragma unroll
    for (int m = 8; m; m >>= 1) {
        a0 += __shfl_xor(a0, m); a1 += __shfl_xor(a1, m); sw += __shfl_xor(sw, m);
    }
    if (g == 0) {
        float inv = 1.0f / sw;
        float o0 = a0 * inv + cvt(b2, 0, bf);
        float o1 = a1 * inv + cvt(b2, 1, bf);
        if (bf) {
            ((u32*)out)[n] = (u32)f2bf(o0) | ((u32)f2bf(o1) << 16);
        } else {
            ((float2*)out)[n] = make_float2(o0, o1);
        }
    }
}

extern "C" void kernel_launch(void* const* d_in, const int* in_sizes, int n_in,
                              void* d_out, int out_size, void* d_ws, size_t ws_size,
                              hipStream_t stream) {
    const void* x    = d_in[0];
    const int*  ei   = (const int*)d_in[1];
    const void* W1   = d_in[2];
    const void* a_s1 = d_in[3];
    const void* a_d1 = d_in[4];
    const void* b1   = d_in[5];
    const void* W2   = d_in[6];
    const void* a_s2 = d_in[7];
    const void* a_d2 = d_in[8];
    const void* b2   = d_in[9];

    // ---- ws carve: ~21.9 MB ----
    char* p = (char*)d_ws;
    int*   degs = (int*)p;     p += ((size_t)N_NODES * 4 + 255) & ~255;           // 200 KB
    u16*   csr  = (u16*)p;     p += (size_t)N_NODES * STRIDE * 2;                 // 6.4 MB
    size_t init_bytes = (size_t)(p - (char*)d_ws);    // degs + csr, one 0xFF memset
    u32*   h1u  = (u32*)p;     p += (size_t)(N_NODES + 1) * 64 * 4;               // 12.8 MB (+ row N)
    float* as1  = (float*)p;   p += (size_t)(N_NODES + 1) * HEADS * 4;            // + sentinel
    float* ad1  = (float*)p;   p += (size_t)N_NODES * HEADS * 4;
    float* h2   = (float*)p;   p += (size_t)N_NODES * 2 * 4;
    float* as2  = (float*)p;   p += (size_t)N_NODES * 4;
    float* ad2  = (float*)p;   p += (size_t)N_NODES * 4;

    // ONE memset: degs -> -1 (rank base), csr -> 0xFFFF (pad sentinels)
    hipMemsetAsync(degs, 0xFF, init_bytes, stream);

    // sliced deg+fill and h1 co-dispatched (independent of each other)
    k_fill_h1<<<FILL_BLOCKS + H1_BLOCKS, 256, 0, stream>>>(
        x, ei, W1, a_s1, a_d1, degs, csr, h1u, as1, ad1);
    k_gather1<<<N_NODES / 4, 256, 0, stream>>>(
        x, degs, csr, h1u, as1, ad1, b1, W2, a_s2, a_d2, h2, as2, ad2);
    k_gather2<<<N_NODES / 16, 256, 0, stream>>>(
        x, degs, csr, h2, as2, ad2, b2, d_out);
}